// Round 13
// baseline (234.118 us; speedup 1.0000x reference)
//
#include <hip/hip_runtime.h>
#include <math.h>

#define NSEQ 2048
#define DMOD 1024
#define NBATCH 4
#define NHEAD 16
#define NFREQ 1025

typedef unsigned short u16t;
typedef __attribute__((ext_vector_type(8))) short short8;
typedef __attribute__((ext_vector_type(4))) float f32x4;

__device__ __forceinline__ float gelu_exact(float x) {
  return 0.5f * x * (1.0f + erff(x * 0.70710678118654752440f));
}
__device__ __forceinline__ u16t bf16_rtn(float x) {
  unsigned u = __float_as_uint(x);
  return (u16t)((u + 0x7FFFu + ((u >> 16) & 1u)) >> 16);
}
__device__ __forceinline__ float bf16f(u16t h) {
  return __uint_as_float(((unsigned)h) << 16);
}
__device__ __forceinline__ void gload_lds16(const u16t* g, u16t* l) {
  __builtin_amdgcn_global_load_lds(
      (const __attribute__((address_space(1))) void*)g,
      (__attribute__((address_space(3))) void*)l, 16, 0, 0);
}

// ---------------- prep: split x + transpose/split Wv, Wp1 (one launch) ----------------
__global__ __launch_bounds__(256) void prep_kernel(
    const float* __restrict__ x, u16t* __restrict__ x_hi, u16t* __restrict__ x_lo,
    const float* __restrict__ Wv, u16t* __restrict__ Tvh, u16t* __restrict__ Tvl,
    const float* __restrict__ Wp1, u16t* __restrict__ Tph, u16t* __restrict__ Tpl) {
  __shared__ float tile[32][33];
  int bx = blockIdx.x;
  int tid = threadIdx.x;
  if (bx < 2048) {
    const int n8 = (NBATCH * NSEQ * DMOD) / 8;
    for (int i = bx * 256 + tid; i < n8; i += 2048 * 256) {
      const float4* p = reinterpret_cast<const float4*>(x + (size_t)i * 8);
      float4 a = p[0], b = p[1];
      float vv[8] = {a.x, a.y, a.z, a.w, b.x, b.y, b.z, b.w};
      alignas(16) u16t th[8];
      alignas(16) u16t tl[8];
#pragma unroll
      for (int e = 0; e < 8; ++e) {
        u16t h = bf16_rtn(vv[e]);
        th[e] = h;
        tl[e] = bf16_rtn(vv[e] - bf16f(h));
      }
      *reinterpret_cast<uint4*>(x_hi + (size_t)i * 8) = *reinterpret_cast<const uint4*>(th);
      *reinterpret_cast<uint4*>(x_lo + (size_t)i * 8) = *reinterpret_cast<const uint4*>(tl);
    }
  } else {
    int idx = bx - 2048;                 // 0..1279 = 40 ncols x 32 krows
    int wcol = idx % 40, k0 = (idx / 40) * 32;
    const float* W; u16t* Th; u16t* Tl; int N, n0;
    if (wcol < 32) { W = Wv;  Th = Tvh; Tl = Tvl; N = 1024; n0 = wcol * 32; }
    else           { W = Wp1; Th = Tph; Tl = Tpl; N = 256;  n0 = (wcol - 32) * 32; }
    const int K = 1024;
    int r = tid >> 5, c = tid & 31;
#pragma unroll
    for (int i = 0; i < 4; ++i)
      tile[r + 8 * i][c] = W[(size_t)(k0 + r + 8 * i) * N + n0 + c];
    __syncthreads();
#pragma unroll
    for (int i = 0; i < 4; ++i) {
      int rr = r + 8 * i;
      float v = tile[c][rr];
      u16t h = bf16_rtn(v);
      Th[(size_t)(n0 + rr) * K + k0 + c] = h;
      Tl[(size_t)(n0 + rr) * K + k0 + c] = bf16_rtn(v - bf16f(h));
    }
  }
}

// ---------------- fused GEMM: vT (128x128 tile) + p-score (128x32 tile) ----------------
__global__ __launch_bounds__(256) void gemm_fused_kernel(
    const u16t* __restrict__ Ah_g, const u16t* __restrict__ Al_g,
    const u16t* __restrict__ Bvh, const u16t* __restrict__ Bvl,
    const u16t* __restrict__ Bph, const u16t* __restrict__ Bpl,
    const float* __restrict__ bv, const float* __restrict__ bp1,
    const float* __restrict__ Wp2,
    float* __restrict__ vT, float* __restrict__ s_part) {
  __shared__ u16t Ahs[128 * 64], Als[128 * 64], Bhs[128 * 64], Bls[128 * 64]; // 64 KB
  __shared__ u16t Php[32 * 64], Ppl[32 * 64];                                 // 8 KB
  const int tid = threadIdx.x;
  const int lane = tid & 63, wave = tid >> 6;
  const int lr = lane & 15, lg = lane >> 4;
  const int wm0 = (wave >> 1) * 64, wn0 = (wave & 1) * 64;
  const int nwg = gridDim.x;
  const int L = (blockIdx.x & 7) * (nwg >> 3) + (blockIdx.x >> 3);
  const int m0 = (L >> 3) * 128;
  const int nblk = L & 7;
  const int n0 = nblk * 128;
  const int pc0 = nblk * 32;
  const int K = 1024;

  f32x4 acc[4][4];
#pragma unroll
  for (int i = 0; i < 4; ++i)
#pragma unroll
    for (int j = 0; j < 4; ++j) acc[i][j] = 0.0f;
  f32x4 accp[2][2];
#pragma unroll
  for (int i = 0; i < 2; ++i)
#pragma unroll
    for (int j = 0; j < 2; ++j) accp[i][j] = 0.0f;

  for (int k0 = 0; k0 < K; k0 += 64) {
#pragma unroll
    for (int q = 0; q < 4; ++q) {
      int cid = q * 256 + tid;
      int row = cid >> 3, grp = cid & 7;
      int koff = k0 + ((grp ^ (row & 7)) << 3);
      size_t ea = (size_t)(m0 + row) * K + koff;
      size_t eb = (size_t)(n0 + row) * K + koff;
      int lbase = q * 2048 + wave * 512;
      gload_lds16(Ah_g + ea, Ahs + lbase);
      gload_lds16(Al_g + ea, Als + lbase);
      gload_lds16(Bvh + eb, Bhs + lbase);
      gload_lds16(Bvl + eb, Bls + lbase);
    }
    {
      int row = tid >> 3, grp = tid & 7;
      int koff = k0 + ((grp ^ (row & 7)) << 3);
      size_t ep = (size_t)(pc0 + row) * K + koff;
      int lbase = wave * 512;
      gload_lds16(Bph + ep, Php + lbase);
      gload_lds16(Bpl + ep, Ppl + lbase);
    }
    __syncthreads();
#pragma unroll
    for (int kf = 0; kf < 2; ++kf) {
      short8 ah[4], al[4];
#pragma unroll
      for (int mi = 0; mi < 4; ++mi) {
        int r_ = wm0 + mi * 16 + lr;
        int g = (kf * 4 + lg) ^ (r_ & 7);
        ah[mi] = *reinterpret_cast<const short8*>(&Ahs[r_ * 64 + g * 8]);
        al[mi] = *reinterpret_cast<const short8*>(&Als[r_ * 64 + g * 8]);
      }
#pragma unroll
      for (int ni = 0; ni < 4; ++ni) {
        int r_ = wn0 + ni * 16 + lr;
        int g = (kf * 4 + lg) ^ (r_ & 7);
        short8 bh8 = *reinterpret_cast<const short8*>(&Bhs[r_ * 64 + g * 8]);
        short8 bl8 = *reinterpret_cast<const short8*>(&Bls[r_ * 64 + g * 8]);
#pragma unroll
        for (int mi = 0; mi < 4; ++mi) {
          acc[mi][ni] = __builtin_amdgcn_mfma_f32_16x16x32_bf16(ah[mi], bh8, acc[mi][ni], 0, 0, 0);
          acc[mi][ni] = __builtin_amdgcn_mfma_f32_16x16x32_bf16(ah[mi], bl8, acc[mi][ni], 0, 0, 0);
          acc[mi][ni] = __builtin_amdgcn_mfma_f32_16x16x32_bf16(al[mi], bh8, acc[mi][ni], 0, 0, 0);
        }
      }
      short8 pah[2], pal[2];
#pragma unroll
      for (int mi = 0; mi < 2; ++mi) {
        int r_ = wave * 32 + mi * 16 + lr;
        int g = (kf * 4 + lg) ^ (r_ & 7);
        pah[mi] = *reinterpret_cast<const short8*>(&Ahs[r_ * 64 + g * 8]);
        pal[mi] = *reinterpret_cast<const short8*>(&Als[r_ * 64 + g * 8]);
      }
#pragma unroll
      for (int ni = 0; ni < 2; ++ni) {
        int r_ = ni * 16 + lr;
        int g = (kf * 4 + lg) ^ (r_ & 7);
        short8 pbh = *reinterpret_cast<const short8*>(&Php[r_ * 64 + g * 8]);
        short8 pbl = *reinterpret_cast<const short8*>(&Ppl[r_ * 64 + g * 8]);
#pragma unroll
        for (int mi = 0; mi < 2; ++mi) {
          accp[mi][ni] = __builtin_amdgcn_mfma_f32_16x16x32_bf16(pah[mi], pbh, accp[mi][ni], 0, 0, 0);
          accp[mi][ni] = __builtin_amdgcn_mfma_f32_16x16x32_bf16(pah[mi], pbl, accp[mi][ni], 0, 0, 0);
          accp[mi][ni] = __builtin_amdgcn_mfma_f32_16x16x32_bf16(pal[mi], pbh, accp[mi][ni], 0, 0, 0);
        }
      }
    }
    __syncthreads();
  }
#pragma unroll
  for (int mi = 0; mi < 4; ++mi)
#pragma unroll
    for (int ni = 0; ni < 4; ++ni) {
      int col = n0 + wn0 + ni * 16 + lr;
      float bvv = bv[col];
      f32x4 a = acc[mi][ni];
      int mbase = m0 + wm0 + mi * 16 + lg * 4;
      int b = mbase >> 11, ss = mbase & 2047;
      float4 o4;
      o4.x = a[0] + bvv; o4.y = a[1] + bvv; o4.z = a[2] + bvv; o4.w = a[3] + bvv;
      *reinterpret_cast<float4*>(vT + (size_t)b * (DMOD * NSEQ) + (size_t)col * NSEQ + ss) = o4;
    }
  {
    float w2[2], bcol[2];
#pragma unroll
    for (int ni = 0; ni < 2; ++ni) {
      int col = pc0 + ni * 16 + lr;
      w2[ni] = Wp2[col];
      bcol[ni] = bp1[col];
    }
#pragma unroll
    for (int mi = 0; mi < 2; ++mi)
#pragma unroll
      for (int r = 0; r < 4; ++r) {
        float p = 0.f;
#pragma unroll
        for (int ni = 0; ni < 2; ++ni)
          p = fmaf(gelu_exact(accp[mi][ni][r] + bcol[ni]), w2[ni], p);
        p += __shfl_xor(p, 1);
        p += __shfl_xor(p, 2);
        p += __shfl_xor(p, 4);
        p += __shfl_xor(p, 8);
        if (lr == 0) {
          int row = m0 + wave * 32 + mi * 16 + lg * 4 + r;
          s_part[nblk * 8192 + row] = p;
        }
      }
  }
}

// ---------------- plain split-bf16 MFMA GEMM (BK=64, XCD swizzle), fp32 out ----------------
template<int NBLK>
__global__ __launch_bounds__(256) void mfma_gemm(
    const u16t* __restrict__ Ah_g, const u16t* __restrict__ Al_g,
    const u16t* __restrict__ Bh_g, const u16t* __restrict__ Bl_g,
    const float* __restrict__ bias,
    float* __restrict__ Cf,
    int N, int K) {
  __shared__ u16t Ahs[128 * 64], Als[128 * 64], Bhs[128 * 64], Bls[128 * 64]; // 64 KB
  const int tid = threadIdx.x;
  const int lane = tid & 63, wave = tid >> 6;
  const int lr = lane & 15, lg = lane >> 4;
  const int wm0 = (wave >> 1) * 64, wn0 = (wave & 1) * 64;
  const int nwg = gridDim.x;
  const int L = (blockIdx.x & 7) * (nwg >> 3) + (blockIdx.x >> 3);
  const int m0 = (L / NBLK) * 128, n0 = (L % NBLK) * 128;

  f32x4 acc[4][4];
#pragma unroll
  for (int i = 0; i < 4; ++i)
#pragma unroll
    for (int j = 0; j < 4; ++j) acc[i][j] = 0.0f;

  for (int k0 = 0; k0 < K; k0 += 64) {
#pragma unroll
    for (int q = 0; q < 4; ++q) {
      int cid = q * 256 + tid;
      int row = cid >> 3, grp = cid & 7;
      int koff = k0 + ((grp ^ (row & 7)) << 3);
      size_t ea = (size_t)(m0 + row) * K + koff;
      size_t eb = (size_t)(n0 + row) * K + koff;
      int lbase = q * 2048 + wave * 512;
      gload_lds16(Ah_g + ea, Ahs + lbase);
      gload_lds16(Al_g + ea, Als + lbase);
      gload_lds16(Bh_g + eb, Bhs + lbase);
      gload_lds16(Bl_g + eb, Bls + lbase);
    }
    __syncthreads();
#pragma unroll
    for (int kf = 0; kf < 2; ++kf) {
      short8 ah[4], al[4];
#pragma unroll
      for (int mi = 0; mi < 4; ++mi) {
        int r_ = wm0 + mi * 16 + lr;
        int g = (kf * 4 + lg) ^ (r_ & 7);
        ah[mi] = *reinterpret_cast<const short8*>(&Ahs[r_ * 64 + g * 8]);
        al[mi] = *reinterpret_cast<const short8*>(&Als[r_ * 64 + g * 8]);
      }
#pragma unroll
      for (int ni = 0; ni < 4; ++ni) {
        int r_ = wn0 + ni * 16 + lr;
        int g = (kf * 4 + lg) ^ (r_ & 7);
        short8 bh8 = *reinterpret_cast<const short8*>(&Bhs[r_ * 64 + g * 8]);
        short8 bl8 = *reinterpret_cast<const short8*>(&Bls[r_ * 64 + g * 8]);
#pragma unroll
        for (int mi = 0; mi < 4; ++mi) {
          acc[mi][ni] = __builtin_amdgcn_mfma_f32_16x16x32_bf16(ah[mi], bh8, acc[mi][ni], 0, 0, 0);
          acc[mi][ni] = __builtin_amdgcn_mfma_f32_16x16x32_bf16(ah[mi], bl8, acc[mi][ni], 0, 0, 0);
          acc[mi][ni] = __builtin_amdgcn_mfma_f32_16x16x32_bf16(al[mi], bh8, acc[mi][ni], 0, 0, 0);
        }
      }
    }
    __syncthreads();
  }
#pragma unroll
  for (int mi = 0; mi < 4; ++mi)
#pragma unroll
    for (int ni = 0; ni < 4; ++ni) {
      int col = n0 + wn0 + ni * 16 + lr;
      float bvv = bias[col];
      f32x4 a = acc[mi][ni];
#pragma unroll
      for (int r = 0; r < 4; ++r) {
        int row = m0 + wm0 + mi * 16 + lg * 4 + r;
        Cf[(size_t)row * N + col] = a[r] + bvv;
      }
    }
}

// ---------------- fused rFFT * gate * irFFT, register-resident FFT (4-wave, in place) ----------------
#define PADI(i) ((i) + ((i) >> 5))

template<int HJ, int TWS>
__device__ __forceinline__ void fwd_reg_stage(float* vr, float* vi,
    const float* TWr, const float* TWi, int lane) {
  float twr_[HJ], twi_[HJ];
#pragma unroll
  for (int t = 0; t < HJ; ++t) {
    int m = (t * 64 + lane) * TWS;
    twr_[t] = TWr[PADI(m)]; twi_[t] = TWi[PADI(m)];
  }
#pragma unroll
  for (int j = 0; j < 16; ++j) {
    if (j & HJ) continue;
    int t = j & (HJ - 1);
    float ur = vr[j], ui = vi[j];
    float wr = vr[j + HJ], wi = vi[j + HJ];
    float dr = ur - wr, di = ui - wi;
    vr[j] = ur + wr; vi[j] = ui + wi;
    vr[j + HJ] = dr * twr_[t] - di * twi_[t];
    vi[j + HJ] = dr * twi_[t] + di * twr_[t];
  }
}

template<int S, int TWS>
__device__ __forceinline__ void fwd_lane_stage(float* vr, float* vi,
    const float* TWr, const float* TWi, int lane) {
  float twr_ = 1.0f, twi_ = 0.0f;
  if (S > 1) {
    int m = (lane & (S - 1)) * TWS;
    twr_ = TWr[PADI(m)]; twi_ = TWi[PADI(m)];
  }
  bool hi = (lane & S) != 0;
#pragma unroll
  for (int j = 0; j < 16; ++j) {
    float or_ = __shfl_xor(vr[j], S, 64);
    float oi_ = __shfl_xor(vi[j], S, 64);
    float sr = vr[j] + or_, si_ = vi[j] + oi_;
    float dr = or_ - vr[j], di = oi_ - vi[j];
    float rr = dr * twr_ - di * twi_;
    float ri = dr * twi_ + di * twr_;
    vr[j] = hi ? rr : sr;
    vi[j] = hi ? ri : si_;
  }
}

template<int S, int TWS>
__device__ __forceinline__ void inv_lane_stage(float* vr, float* vi,
    const float* TWr, const float* TWi, int lane) {
  float twr_ = 1.0f, twi_ = 0.0f;
  if (S > 1) {
    int m = (lane & (S - 1)) * TWS;
    twr_ = TWr[PADI(m)]; twi_ = -TWi[PADI(m)];
  }
  bool hi = (lane & S) != 0;
#pragma unroll
  for (int j = 0; j < 16; ++j) {
    float xr = vr[j], xi = vi[j];
    if (S > 1) {
      float pr = xr * twr_ - xi * twi_;
      float pi = xr * twi_ + xi * twr_;
      xr = hi ? pr : xr;
      xi = hi ? pi : xi;
    }
    float or_ = __shfl_xor(xr, S, 64);
    float oi_ = __shfl_xor(xi, S, 64);
    vr[j] = hi ? (or_ - xr) : (xr + or_);
    vi[j] = hi ? (oi_ - xi) : (xi + oi_);
  }
}

template<int HJ, int TWS>
__device__ __forceinline__ void inv_reg_stage(float* vr, float* vi,
    const float* TWr, const float* TWi, int lane) {
  float twr_[HJ], twi_[HJ];
#pragma unroll
  for (int t = 0; t < HJ; ++t) {
    int m = (t * 64 + lane) * TWS;
    twr_[t] = TWr[PADI(m)]; twi_[t] = -TWi[PADI(m)];
  }
#pragma unroll
  for (int j = 0; j < 16; ++j) {
    if (j & HJ) continue;
    int t = j & (HJ - 1);
    float ur = vr[j], ui = vi[j];
    float br = vr[j + HJ], bi = vi[j + HJ];
    float wr = br * twr_[t] - bi * twi_[t];
    float wi = br * twi_[t] + bi * twr_[t];
    vr[j] = ur + wr; vi[j] = ui + wi;
    vr[j + HJ] = ur - wr; vi[j + HJ] = ui - wi;
  }
}

__global__ __launch_bounds__(256) void conv_fft_kernel(
    float* __restrict__ vio, const float* __restrict__ gateb) {
  __shared__ float Zr[4][1056], Zi[4][1056];
  __shared__ float TWr[528], TWi[528];
  const int tid = threadIdx.x;
  const int lane = tid & 63, wave = tid >> 6;
  const int c0 = blockIdx.x * 4;
  const int b = blockIdx.y;
  const int bh = b * NHEAD + (c0 >> 6);
  const float* gate_bh = gateb + (size_t)bh * NFREQ * 2;

#pragma unroll
  for (int q = 0; q < 2; ++q) {
    int m = q * 256 + tid;
    float si, co;
    sincosf(-3.14159265358979323846f * (float)m * (1.0f / 512.0f), &si, &co);
    TWr[PADI(m)] = co; TWi[PADI(m)] = si;
  }
  __syncthreads();

  float* zr = Zr[wave];
  float* zi = Zi[wave];
  float* col = vio + ((size_t)b * DMOD + (c0 + wave)) * NSEQ;

  float vr[16], vi[16];
#pragma unroll
  for (int j = 0; j < 16; ++j) {
    float2 w2 = *reinterpret_cast<const float2*>(col + 2 * (j * 64 + lane));
    vr[j] = w2.x; vi[j] = w2.y;
  }

  fwd_reg_stage<8, 1>(vr, vi, TWr, TWi, lane);
  fwd_reg_stage<4, 2>(vr, vi, TWr, TWi, lane);
  fwd_reg_stage<2, 4>(vr, vi, TWr, TWi, lane);
  fwd_reg_stage<1, 8>(vr, vi, TWr, TWi, lane);
  fwd_lane_stage<32, 16>(vr, vi, TWr, TWi, lane);
  fwd_lane_stage<16, 32>(vr, vi, TWr, TWi, lane);
  fwd_lane_stage<8, 64>(vr, vi, TWr, TWi, lane);
  fwd_lane_stage<4, 128>(vr, vi, TWr, TWi, lane);
  fwd_lane_stage<2, 256>(vr, vi, TWr, TWi, lane);
  fwd_lane_stage<1, 0>(vr, vi, TWr, TWi, lane);

#pragma unroll
  for (int j = 0; j < 16; ++j) {
    int p = PADI(j * 64 + lane);
    zr[p] = vr[j]; zi[p] = vi[j];
  }
  asm volatile("s_waitcnt lgkmcnt(0)" ::: "memory");

  const float s1 = 1.0f / 1024.0f;
#pragma unroll
  for (int q = 0; q < 8; ++q) {
    int k = q * 64 + lane;
    if (k == 0) {
      float z0r = zr[0], z0i = zi[0];
      float X0 = z0r + z0i;
      float XN = z0r - z0i;
      float2 G0 = *reinterpret_cast<const float2*>(gate_bh + 0);
      float2 GN = *reinterpret_cast<const float2*>(gate_bh + 1024 * 2);
      float y0 = X0 * G0.x * s1;
      float yN = XN * GN.x * s1;
      zr[0] = 0.5f * (y0 + yN); zi[0] = 0.5f * (y0 - yN);
      float zmr = zr[1], zmi = zi[1];
      float X5r = zmr, X5i = -zmi;
      float2 G5 = *reinterpret_cast<const float2*>(gate_bh + 512 * 2);
      float Y5r = (X5r * G5.x - X5i * G5.y) * s1;
      float Y5i = (X5r * G5.y + X5i * G5.x) * s1;
      zr[1] = Y5r; zi[1] = -Y5i;
    } else {
      int kq = 1024 - k;
      int rp = PADI((int)(__brev((unsigned)k) >> 22));
      int rq = PADI((int)(__brev((unsigned)kq) >> 22));
      float Zkr = zr[rp], Zki = zi[rp];
      float Zqr = zr[rq], Zqi = zi[rq];
      float Er = 0.5f * (Zkr + Zqr), Ei = 0.5f * (Zki - Zqi);
      float Odr = 0.5f * (Zki + Zqi), Odi = -0.5f * (Zkr - Zqr);
      float ti, tr;
      sincosf(-3.14159265358979323846f * (float)k * (1.0f / 1024.0f), &ti, &tr);
      float Pr = Odr * tr - Odi * ti, Pi = Odr * ti + Odi * tr;
      float Xkr = Er + Pr, Xki = Ei + Pi;
      float Xqr = Er - Pr, Xqi = -(Ei - Pi);
      float2 Gk = *reinterpret_cast<const float2*>(gate_bh + k * 2);
      float2 Gq = *reinterpret_cast<const float2*>(gate_bh + kq * 2);
      float Ykr = (Xkr * Gk.x - Xki * Gk.y) * s1;
      float Yki = (Xkr * Gk.y + Xki * Gk.x) * s1;
      float Yqr = (Xqr * Gq.x - Xqi * Gq.y) * s1;
      float Yqi = (Xqr * Gq.y + Xqi * Gq.x) * s1;
      float E2r = 0.5f * (Ykr + Yqr), E2i = 0.5f * (Yki - Yqi);
      float D2r = 0.5f * (Ykr - Yqr), D2i = 0.5f * (Yki + Yqi);
      float O2r = D2r * tr + D2i * ti, O2i = D2i * tr - D2r * ti;
      zr[rp] = E2r - O2i; zi[rp] = E2i + O2r;
      zr[rq] = E2r + O2i; zi[rq] = O2r - E2i;
    }
  }
  asm volatile("s_waitcnt lgkmcnt(0)" ::: "memory");

#pragma unroll
  for (int j = 0; j < 16; ++j) {
    int p = PADI(j * 64 + lane);
    vr[j] = zr[p]; vi[j] = zi[p];
  }
  asm volatile("s_waitcnt lgkmcnt(0)" ::: "memory");

  inv_lane_stage<1, 0>(vr, vi, TWr, TWi, lane);
  inv_lane_stage<2, 256>(vr, vi, TWr, TWi, lane);
  inv_lane_stage<4, 128>(vr, vi, TWr, TWi, lane);
  inv_lane_stage<8, 64>(vr, vi, TWr, TWi, lane);
  inv_lane_stage<16, 32>(vr, vi, TWr, TWi, lane);
  inv_lane_stage<32, 16>(vr, vi, TWr, TWi, lane);
  inv_reg_stage<1, 8>(vr, vi, TWr, TWi, lane);
  inv_reg_stage<2, 4>(vr, vi, TWr, TWi, lane);
  inv_reg_stage<4, 2>(vr, vi, TWr, TWi, lane);
  inv_reg_stage<8, 1>(vr, vi, TWr, TWi, lane);

#pragma unroll
  for (int j = 0; j < 16; ++j) {
    *reinterpret_cast<float2*>(col + 2 * (j * 64 + lane)) = make_float2(vr[j], vi[j]);
  }
}

// ---------------- transpose + split: yT[b][c][t] fp32 -> y{h,l}[b][t][c] bf16 ----------------
__global__ __launch_bounds__(256) void tysplit_kernel(
    const float* __restrict__ yT, u16t* __restrict__ yh, u16t* __restrict__ yl) {
  __shared__ float tile[64][65];
  int t0 = blockIdx.x * 64, c0 = blockIdx.y * 64, b = blockIdx.z;
  int r = threadIdx.x >> 4;
  int cc = (threadIdx.x & 15) * 4;
#pragma unroll
  for (int i = 0; i < 4; ++i) {
    int row = r + 16 * i;
    float4 w = *reinterpret_cast<const float4*>(
        yT + ((size_t)b * DMOD + c0 + row) * NSEQ + t0 + cc);
    tile[row][cc] = w.x; tile[row][cc + 1] = w.y;
    tile[row][cc + 2] = w.z; tile[row][cc + 3] = w.w;
  }
  __syncthreads();
#pragma unroll
  for (int i = 0; i < 4; ++i) {
    int tt = r + 16 * i;
    alignas(8) u16t hh[4], ll[4];
#pragma unroll
    for (int e = 0; e < 4; ++e) {
      float v = tile[cc + e][tt];
      u16t h = bf16_rtn(v);
      hh[e] = h;
      ll[e] = bf16_rtn(v - bf16f(h));
    }
    size_t o = ((size_t)b * NSEQ + t0 + tt) * DMOD + c0 + cc;
    *reinterpret_cast<ushort4*>(yh + o) = *reinterpret_cast<const ushort4*>(hh);
    *reinterpret_cast<ushort4*>(yl + o) = *reinterpret_cast<const ushort4*>(ll);
  }
}

// ---------------- Wo transpose + pooled g partials (one launch) ----------------
__global__ __launch_bounds__(256) void wo_pool_kernel(
    const float* __restrict__ Wo, u16t* __restrict__ Toh, u16t* __restrict__ Tol,
    const float* __restrict__ x, const float* __restrict__ s_part,
    const float* __restrict__ bp2, float* __restrict__ gpart) {
  __shared__ float tile[32][33];
  __shared__ float red[256];
  __shared__ float wsh[128];
  int bx = blockIdx.x;
  int tid = threadIdx.x;
  if (bx < 1024) {
    int n0 = (bx & 31) * 32, k0 = (bx >> 5) * 32;
    int r = tid >> 5, c = tid & 31;
#pragma unroll
    for (int i = 0; i < 4; ++i)
      tile[r + 8 * i][c] = Wo[(size_t)(k0 + r + 8 * i) * 1024 + n0 + c];
    __syncthreads();
#pragma unroll
    for (int i = 0; i < 4; ++i) {
      int rr = r + 8 * i;
      float v = tile[c][rr];
      u16t h = bf16_rtn(v);
      Toh[(size_t)(n0 + rr) * 1024 + k0 + c] = h;
      Tol[(size_t)(n0 + rr) * 1024 + k0 + c] = bf16_rtn(v - bf16f(h));
    }
  } else {
    int idx = bx - 1024;            // 0..63
    int chunk = idx & 15, b = idx >> 4;
    float bp = bp2[0];
    float sv[8];
    float m = -1e30f;
#pragma unroll
    for (int q = 0; q < 8; ++q) {
      int row = b * NSEQ + q * 256 + tid;
      float v = bp;
#pragma unroll
      for (int c = 0; c < 8; ++c) v += s_part[c * 8192 + row];
      sv[q] = v;
      m = fmaxf(m, v);
    }
    red[tid] = m; __syncthreads();
    for (int o = 128; o; o >>= 1) { if (tid < o) red[tid] = fmaxf(red[tid], red[tid + o]); __syncthreads(); }
    float bm = red[0]; __syncthreads();
    float sum = 0.f;
#pragma unroll
    for (int q = 0; q < 8; ++q) sum += expf(sv[q] - bm);
    red[tid] = sum; __syncthreads();
    for (int o = 128; o; o >>= 1) { if (tid < o) red[tid] += red[tid + o]; __syncthreads(); }
    float inv = 1.0f / red[0];
    __syncthreads();
    int n0 = chunk * 128;
    if (tid < 128) {
      int row = b * NSEQ + n0 + tid;
      float v = bp;
#pragma unroll
      for (int c = 0; c < 8; ++c) v += s_part[c * 8192 + row];
      wsh[tid] = expf(v - bm) * inv;
    }
    __syncthreads();
    float acc[4] = {};
    for (int n = 0; n < 128; ++n) {
      float wn = wsh[n];
      const float* xr = &x[((size_t)b * NSEQ + n0 + n) * DMOD];
#pragma unroll
      for (int q = 0; q < 4; ++q) acc[q] = fmaf(wn, xr[tid + 256 * q], acc[q]);
    }
    float* gp = &gpart[((size_t)b * 16 + chunk) * DMOD];
#pragma unroll
    for (int q = 0; q < 4; ++q) gp[tid + 256 * q] = acc[q];
  }
}

// ---------------- gate: gpart-reduce + MLP1 + gelu + MLP2 + resize + modReLU + conv ----------------
__device__ __forceinline__ float keys_cubic(float x) {
  if (x >= 2.0f) return 0.0f;
  if (x >= 1.0f) return ((-0.5f * x + 2.5f) * x - 4.0f) * x + 2.0f;
  return ((1.5f * x - 2.5f) * x) * x + 1.0f;
}

__global__ __launch_bounds__(256) void gate_kernel(
    const float* __restrict__ gpart, const float* __restrict__ Wg1,
    const float* __restrict__ bg1,
    const float* __restrict__ Wg2, const float* __restrict__ bg2,
    const float* __restrict__ mod_bias,
    const float* __restrict__ kr5, const float* __restrict__ ki5,
    float* __restrict__ gate_out) {
  int bh = blockIdx.x;
  int tid = threadIdx.x;
  __shared__ float g_s[1024];
  __shared__ float hs_s[256];
  __shared__ float anch_s[64];
  __shared__ float ar_[32], ai_[32];
  __shared__ float gr[NFREQ], gi[NFREQ];
  int b = bh >> 4, h = bh & 15;
  for (int d = tid; d < 1024; d += 256) {
    float acc = 0.f;
#pragma unroll
    for (int j = 0; j < 16; ++j)
      acc += gpart[((size_t)b * 16 + j) * DMOD + d];
    g_s[d] = acc;
  }
  __syncthreads();
  {
    float a0 = 0.f, a1 = 0.f, a2 = 0.f, a3 = 0.f;
    for (int i = 0; i < 1024; i += 4) {
      a0 = fmaf(g_s[i], Wg1[(size_t)i * 256 + tid], a0);
      a1 = fmaf(g_s[i + 1], Wg1[(size_t)(i + 1) * 256 + tid], a1);
      a2 = fmaf(g_s[i + 2], Wg1[(size_t)(i + 2) * 256 + tid], a2);
      a3 = fmaf(g_s[i + 3], Wg1[(size_t)(i + 3) * 256 + tid], a3);
    }
    hs_s[tid] = gelu_exact(bg1[tid] + ((a0 + a1) + (a2 + a3)));
  }
  __syncthreads();
  if (tid < 64) {
    int cc = h * 64 + tid;
    float a2 = bg2[cc];
    for (int i = 0; i < 256; ++i) a2 = fmaf(hs_s[i], Wg2[(size_t)i * 1024 + cc], a2);
    anch_s[tid] = a2;
  }
  __syncthreads();
  if (tid < 32) {
    ar_[tid] = anch_s[tid * 2 + 0];
    ai_[tid] = anch_s[tid * 2 + 1];
  }
  __syncthreads();
  const float inv_scale = 32.0f / 1025.0f;
  for (int f = tid; f < NFREQ; f += 256) {
    float c = (f + 0.5f) * inv_scale - 0.5f;
    int j0 = (int)floorf(c) - 1;
    float wr = 0.f, wi = 0.f, wsum = 0.f;
#pragma unroll
    for (int u = 0; u < 4; ++u) {
      int j = j0 + u;
      if (j < 0 || j > 31) continue;
      float w = keys_cubic(fabsf(c - (float)j));
      wsum += w;
      wr = fmaf(w, ar_[j], wr);
      wi = fmaf(w, ai_[j], wi);
    }
    float invw = 1.0f / wsum;
    wr *= invw; wi *= invw;
    float mag = sqrtf(wr * wr + wi * wi);
    float scale = fmaxf(mag + mod_bias[f], 0.0f) / (mag + 1e-8f);
    gr[f] = wr * scale;
    gi[f] = wi * scale;
  }
  __syncthreads();
  float k_r[5], k_i[5];
#pragma unroll
  for (int j = 0; j < 5; ++j) { k_r[j] = kr5[j]; k_i[j] = ki5[j]; }
  for (int f = tid; f < NFREQ; f += 256) {
    float cr = 0.f, ci = 0.f;
#pragma unroll
    for (int j = 0; j < 5; ++j) {
      int idx = f + j - 2;
      if (idx < 0) idx += NFREQ;
      else if (idx >= NFREQ) idx -= NFREQ;
      float a = gr[idx], bb = gi[idx];
      cr = fmaf(k_r[j], a, cr); cr = fmaf(-k_i[j], bb, cr);
      ci = fmaf(k_r[j], bb, ci); ci = fmaf(k_i[j], a, ci);
    }
    gate_out[((size_t)bh * NFREQ + f) * 2 + 0] = cr;
    gate_out[((size_t)bh * NFREQ + f) * 2 + 1] = ci;
  }
}

extern "C" void kernel_launch(void* const* d_in, const int* in_sizes, int n_in,
                              void* d_out, int out_size, void* d_ws, size_t ws_size,
                              hipStream_t stream) {
  const float* x        = (const float*)d_in[0];
  const float* Wv       = (const float*)d_in[1];
  const float* bv       = (const float*)d_in[2];
  const float* Wp1      = (const float*)d_in[3];
  const float* bp1      = (const float*)d_in[4];
  const float* Wp2      = (const float*)d_in[5];
  const float* bp2      = (const float*)d_in[6];
  const float* Wg1      = (const float*)d_in[7];
  const float* bg1      = (const float*)d_in[8];
  const float* Wg2      = (const float*)d_in[9];
  const float* bg2      = (const float*)d_in[10];
  const float* mod_bias = (const float*)d_in[11];
  const float* ckr      = (const float*)d_in[12];
  const float* cki      = (const float*)d_in[13];
  const float* Wo       = (const float*)d_in[14];
  const float* bo       = (const float*)d_in[15];

  const int M = NBATCH * NSEQ;          // 8192
  const size_t MD = (size_t)M * DMOD;   // 8M elems
  char* wsb = (char*)d_ws;

  // ---- ws layout (peak ~37.25 MB, lifetime-aliased) ----
  u16t* x_hi = (u16t*)wsb;                               // [0,16M)   ; later y_hi
  u16t* x_lo = x_hi + MD;                                // [16M,32M) ; later y_lo
  u16t* y_hi = x_hi;
  u16t* y_lo = x_lo;
  u16t* WT_h = (u16t*)(wsb + (size_t)32 * 1024 * 1024);  // [32M,34M) Wv^T, then Wo^T
  u16t* WT_l = (u16t*)(wsb + (size_t)34 * 1024 * 1024);  // [34M,36M)
  u16t* WTp1_h = (u16t*)(wsb + (size_t)36 * 1024 * 1024);          // [36M,36.5M)
  u16t* WTp1_l = (u16t*)(wsb + (size_t)36 * 1024 * 1024 + 524288); // [36.5M,37M)
  float* s_part = (float*)(wsb + (size_t)37 * 1024 * 1024);        // 256 KB [37M,37.25M)
  // after fused GEMM, WTp1 window [36M,37M) dead -> gpart/gateb (769 KB):
  float* gpart = (float*)(wsb + (size_t)36 * 1024 * 1024);         // 256 KB
  float* gateb = gpart + 65536;                                    // 513 KB

  // d_out staging: vT fp32 (32 MB, in-place FFT -> yT) -> final out fp32
  float* vT  = (float*)d_out;
  float* out = (float*)d_out;

  dim3 blk(256);

  // 1. prep: split x + transposes Wv^T, Wp1^T
  prep_kernel<<<dim3(2048 + 1280), blk, 0, stream>>>(
      x, x_hi, x_lo, Wv, WT_h, WT_l, Wp1, WTp1_h, WTp1_l);
  // 2. fused GEMM (512 blocks): vT + s_part
  gemm_fused_kernel<<<dim3(512), blk, 0, stream>>>(
      x_hi, x_lo, WT_h, WT_l, WTp1_h, WTp1_l, bv, bp1, Wp2, vT, s_part);
  // 3. Wo^T (overwrites Wv^T, dead) + pooled g partials (WTp1 window -> gpart)
  wo_pool_kernel<<<dim3(1024 + 64), blk, 0, stream>>>(
      Wo, WT_h, WT_l, x, s_part, bp2, gpart);
  // 4. gate (inline MLP1 + MLP2 + resize + modReLU + conv)
  gate_kernel<<<dim3(NBATCH * NHEAD), blk, 0, stream>>>(
      gpart, Wg1, bg1, Wg2, bg2, mod_bias, ckr, cki, gateb);
  // 5. fused rFFT*gate*irFFT in place on vT -> yT
  conv_fft_kernel<<<dim3(DMOD / 4, NBATCH), blk, 0, stream>>>(vT, gateb);
  // 6. transpose+split: yT -> y split bf16 (overwrites x split; x dead)
  tysplit_kernel<<<dim3(NSEQ / 64, DMOD / 64, NBATCH), blk, 0, stream>>>(vT, y_hi, y_lo);
  // 7. GEMM3: out = y @ Wo + bo (overwrites vT; dead)
  mfma_gemm<8><<<dim3((DMOD / 128) * (M / 128)), blk, 0, stream>>>(
      y_hi, y_lo, WT_h, WT_l, bo, out, DMOD, 1024);
}

// Round 14
// 199.859 us; speedup vs baseline: 1.1714x; 1.1714x over previous
//
#include <hip/hip_runtime.h>
#include <math.h>

#define NSEQ 2048
#define DMOD 1024
#define NBATCH 4
#define NHEAD 16
#define NFREQ 1025

typedef unsigned short u16t;
typedef __attribute__((ext_vector_type(8))) short short8;
typedef __attribute__((ext_vector_type(4))) float f32x4;

__device__ __forceinline__ float gelu_exact(float x) {
  return 0.5f * x * (1.0f + erff(x * 0.70710678118654752440f));
}
__device__ __forceinline__ u16t bf16_rtn(float x) {
  unsigned u = __float_as_uint(x);
  return (u16t)((u + 0x7FFFu + ((u >> 16) & 1u)) >> 16);
}
__device__ __forceinline__ float bf16f(u16t h) {
  return __uint_as_float(((unsigned)h) << 16);
}
__device__ __forceinline__ void gload_lds16(const u16t* g, u16t* l) {
  __builtin_amdgcn_global_load_lds(
      (const __attribute__((address_space(1))) void*)g,
      (__attribute__((address_space(3))) void*)l, 16, 0, 0);
}

// ---------------- elementwise split fp32 -> bf16 hi/lo ----------------
__global__ __launch_bounds__(256) void split_kernel(const float* __restrict__ in,
    u16t* __restrict__ hi, u16t* __restrict__ lo, int n8) {
  for (int i = blockIdx.x * blockDim.x + threadIdx.x; i < n8; i += gridDim.x * blockDim.x) {
    const float4* p = reinterpret_cast<const float4*>(in + (size_t)i * 8);
    float4 a = p[0], b = p[1];
    float vv[8] = {a.x, a.y, a.z, a.w, b.x, b.y, b.z, b.w};
    alignas(16) u16t th[8];
    alignas(16) u16t tl[8];
#pragma unroll
    for (int e = 0; e < 8; ++e) {
      u16t h = bf16_rtn(vv[e]);
      th[e] = h;
      tl[e] = bf16_rtn(vv[e] - bf16f(h));
    }
    *reinterpret_cast<uint4*>(hi + (size_t)i * 8) = *reinterpret_cast<const uint4*>(th);
    *reinterpret_cast<uint4*>(lo + (size_t)i * 8) = *reinterpret_cast<const uint4*>(tl);
  }
}

// ---------------- transpose + split weights: W[K][N] -> T{h,l}[N][K] ----------------
__global__ __launch_bounds__(256) void tsplit_kernel(const float* __restrict__ W,
    u16t* __restrict__ Th, u16t* __restrict__ Tl, int K, int N) {
  __shared__ float tile[32][33];
  int k0 = blockIdx.y * 32, n0 = blockIdx.x * 32;
  int r = threadIdx.x >> 5, c = threadIdx.x & 31;
#pragma unroll
  for (int i = 0; i < 4; ++i)
    tile[r + 8 * i][c] = W[(size_t)(k0 + r + 8 * i) * N + n0 + c];
  __syncthreads();
#pragma unroll
  for (int i = 0; i < 4; ++i) {
    int rr = r + 8 * i;
    float v = tile[c][rr];
    u16t h = bf16_rtn(v);
    Th[(size_t)(n0 + rr) * K + k0 + c] = h;
    Tl[(size_t)(n0 + rr) * K + k0 + c] = bf16_rtn(v - bf16f(h));
  }
}

// ---------------- merged transpose+split for Wv (N=1024) and Wp1 (N=256) ----------------
__global__ __launch_bounds__(256) void tsplit2_kernel(
    const float* __restrict__ Wv, u16t* __restrict__ Tvh, u16t* __restrict__ Tvl,
    const float* __restrict__ Wp, u16t* __restrict__ Tph, u16t* __restrict__ Tpl) {
  __shared__ float tile[32][33];
  int bx = blockIdx.x;
  const float* W; u16t* Th; u16t* Tl; int N, n0;
  if (bx < 32) { W = Wv; Th = Tvh; Tl = Tvl; N = 1024; n0 = bx * 32; }
  else         { W = Wp; Th = Tph; Tl = Tpl; N = 256;  n0 = (bx - 32) * 32; }
  const int K = 1024;
  int k0 = blockIdx.y * 32;
  int r = threadIdx.x >> 5, c = threadIdx.x & 31;
#pragma unroll
  for (int i = 0; i < 4; ++i)
    tile[r + 8 * i][c] = W[(size_t)(k0 + r + 8 * i) * N + n0 + c];
  __syncthreads();
#pragma unroll
  for (int i = 0; i < 4; ++i) {
    int rr = r + 8 * i;
    float v = tile[c][rr];
    u16t h = bf16_rtn(v);
    Th[(size_t)(n0 + rr) * K + k0 + c] = h;
    Tl[(size_t)(n0 + rr) * K + k0 + c] = bf16_rtn(v - bf16f(h));
  }
}

// ---------------- fused GEMM: vT (128x128 tile) + p-score (128x32 tile) ----------------
__global__ __launch_bounds__(256) void gemm_fused_kernel(
    const u16t* __restrict__ Ah_g, const u16t* __restrict__ Al_g,
    const u16t* __restrict__ Bvh, const u16t* __restrict__ Bvl,
    const u16t* __restrict__ Bph, const u16t* __restrict__ Bpl,
    const float* __restrict__ bv, const float* __restrict__ bp1,
    const float* __restrict__ Wp2,
    float* __restrict__ vT, float* __restrict__ s_part) {
  __shared__ u16t Ahs[128 * 64], Als[128 * 64], Bhs[128 * 64], Bls[128 * 64]; // 64 KB
  __shared__ u16t Php[32 * 64], Ppl[32 * 64];                                 // 8 KB
  const int tid = threadIdx.x;
  const int lane = tid & 63, wave = tid >> 6;
  const int lr = lane & 15, lg = lane >> 4;
  const int wm0 = (wave >> 1) * 64, wn0 = (wave & 1) * 64;
  const int nwg = gridDim.x;
  const int L = (blockIdx.x & 7) * (nwg >> 3) + (blockIdx.x >> 3);
  const int m0 = (L >> 3) * 128;
  const int nblk = L & 7;
  const int n0 = nblk * 128;
  const int pc0 = nblk * 32;
  const int K = 1024;

  f32x4 acc[4][4];
#pragma unroll
  for (int i = 0; i < 4; ++i)
#pragma unroll
    for (int j = 0; j < 4; ++j) acc[i][j] = 0.0f;
  f32x4 accp[2][2];
#pragma unroll
  for (int i = 0; i < 2; ++i)
#pragma unroll
    for (int j = 0; j < 2; ++j) accp[i][j] = 0.0f;

  for (int k0 = 0; k0 < K; k0 += 64) {
#pragma unroll
    for (int q = 0; q < 4; ++q) {
      int cid = q * 256 + tid;
      int row = cid >> 3, grp = cid & 7;
      int koff = k0 + ((grp ^ (row & 7)) << 3);
      size_t ea = (size_t)(m0 + row) * K + koff;
      size_t eb = (size_t)(n0 + row) * K + koff;
      int lbase = q * 2048 + wave * 512;
      gload_lds16(Ah_g + ea, Ahs + lbase);
      gload_lds16(Al_g + ea, Als + lbase);
      gload_lds16(Bvh + eb, Bhs + lbase);
      gload_lds16(Bvl + eb, Bls + lbase);
    }
    {
      int row = tid >> 3, grp = tid & 7;
      int koff = k0 + ((grp ^ (row & 7)) << 3);
      size_t ep = (size_t)(pc0 + row) * K + koff;
      int lbase = wave * 512;
      gload_lds16(Bph + ep, Php + lbase);
      gload_lds16(Bpl + ep, Ppl + lbase);
    }
    __syncthreads();
#pragma unroll
    for (int kf = 0; kf < 2; ++kf) {
      short8 ah[4], al[4];
#pragma unroll
      for (int mi = 0; mi < 4; ++mi) {
        int r_ = wm0 + mi * 16 + lr;
        int g = (kf * 4 + lg) ^ (r_ & 7);
        ah[mi] = *reinterpret_cast<const short8*>(&Ahs[r_ * 64 + g * 8]);
        al[mi] = *reinterpret_cast<const short8*>(&Als[r_ * 64 + g * 8]);
      }
#pragma unroll
      for (int ni = 0; ni < 4; ++ni) {
        int r_ = wn0 + ni * 16 + lr;
        int g = (kf * 4 + lg) ^ (r_ & 7);
        short8 bh8 = *reinterpret_cast<const short8*>(&Bhs[r_ * 64 + g * 8]);
        short8 bl8 = *reinterpret_cast<const short8*>(&Bls[r_ * 64 + g * 8]);
#pragma unroll
        for (int mi = 0; mi < 4; ++mi) {
          acc[mi][ni] = __builtin_amdgcn_mfma_f32_16x16x32_bf16(ah[mi], bh8, acc[mi][ni], 0, 0, 0);
          acc[mi][ni] = __builtin_amdgcn_mfma_f32_16x16x32_bf16(ah[mi], bl8, acc[mi][ni], 0, 0, 0);
          acc[mi][ni] = __builtin_amdgcn_mfma_f32_16x16x32_bf16(al[mi], bh8, acc[mi][ni], 0, 0, 0);
        }
      }
      short8 pah[2], pal[2];
#pragma unroll
      for (int mi = 0; mi < 2; ++mi) {
        int r_ = wave * 32 + mi * 16 + lr;
        int g = (kf * 4 + lg) ^ (r_ & 7);
        pah[mi] = *reinterpret_cast<const short8*>(&Ahs[r_ * 64 + g * 8]);
        pal[mi] = *reinterpret_cast<const short8*>(&Als[r_ * 64 + g * 8]);
      }
#pragma unroll
      for (int ni = 0; ni < 2; ++ni) {
        int r_ = ni * 16 + lr;
        int g = (kf * 4 + lg) ^ (r_ & 7);
        short8 pbh = *reinterpret_cast<const short8*>(&Php[r_ * 64 + g * 8]);
        short8 pbl = *reinterpret_cast<const short8*>(&Ppl[r_ * 64 + g * 8]);
#pragma unroll
        for (int mi = 0; mi < 2; ++mi) {
          accp[mi][ni] = __builtin_amdgcn_mfma_f32_16x16x32_bf16(pah[mi], pbh, accp[mi][ni], 0, 0, 0);
          accp[mi][ni] = __builtin_amdgcn_mfma_f32_16x16x32_bf16(pah[mi], pbl, accp[mi][ni], 0, 0, 0);
          accp[mi][ni] = __builtin_amdgcn_mfma_f32_16x16x32_bf16(pal[mi], pbh, accp[mi][ni], 0, 0, 0);
        }
      }
    }
    __syncthreads();
  }
#pragma unroll
  for (int mi = 0; mi < 4; ++mi)
#pragma unroll
    for (int ni = 0; ni < 4; ++ni) {
      int col = n0 + wn0 + ni * 16 + lr;
      float bvv = bv[col];
      f32x4 a = acc[mi][ni];
      int mbase = m0 + wm0 + mi * 16 + lg * 4;
      int b = mbase >> 11, ss = mbase & 2047;
      float4 o4;
      o4.x = a[0] + bvv; o4.y = a[1] + bvv; o4.z = a[2] + bvv; o4.w = a[3] + bvv;
      *reinterpret_cast<float4*>(vT + (size_t)b * (DMOD * NSEQ) + (size_t)col * NSEQ + ss) = o4;
    }
  {
    float w2[2], bcol[2];
#pragma unroll
    for (int ni = 0; ni < 2; ++ni) {
      int col = pc0 + ni * 16 + lr;
      w2[ni] = Wp2[col];
      bcol[ni] = bp1[col];
    }
#pragma unroll
    for (int mi = 0; mi < 2; ++mi)
#pragma unroll
      for (int r = 0; r < 4; ++r) {
        float p = 0.f;
#pragma unroll
        for (int ni = 0; ni < 2; ++ni)
          p = fmaf(gelu_exact(accp[mi][ni][r] + bcol[ni]), w2[ni], p);
        p += __shfl_xor(p, 1);
        p += __shfl_xor(p, 2);
        p += __shfl_xor(p, 4);
        p += __shfl_xor(p, 8);
        if (lr == 0) {
          int row = m0 + wave * 32 + mi * 16 + lg * 4 + r;
          s_part[nblk * 8192 + row] = p;
        }
      }
  }
}

// ---------------- plain split-bf16 MFMA GEMM (BK=64, XCD swizzle), fp32 out ----------------
template<int NBLK>
__global__ __launch_bounds__(256) void mfma_gemm(
    const u16t* __restrict__ Ah_g, const u16t* __restrict__ Al_g,
    const u16t* __restrict__ Bh_g, const u16t* __restrict__ Bl_g,
    const float* __restrict__ bias,
    float* __restrict__ Cf,
    int N, int K) {
  __shared__ u16t Ahs[128 * 64], Als[128 * 64], Bhs[128 * 64], Bls[128 * 64]; // 64 KB
  const int tid = threadIdx.x;
  const int lane = tid & 63, wave = tid >> 6;
  const int lr = lane & 15, lg = lane >> 4;
  const int wm0 = (wave >> 1) * 64, wn0 = (wave & 1) * 64;
  const int nwg = gridDim.x;
  const int L = (blockIdx.x & 7) * (nwg >> 3) + (blockIdx.x >> 3);
  const int m0 = (L / NBLK) * 128, n0 = (L % NBLK) * 128;

  f32x4 acc[4][4];
#pragma unroll
  for (int i = 0; i < 4; ++i)
#pragma unroll
    for (int j = 0; j < 4; ++j) acc[i][j] = 0.0f;

  for (int k0 = 0; k0 < K; k0 += 64) {
#pragma unroll
    for (int q = 0; q < 4; ++q) {
      int cid = q * 256 + tid;
      int row = cid >> 3, grp = cid & 7;
      int koff = k0 + ((grp ^ (row & 7)) << 3);
      size_t ea = (size_t)(m0 + row) * K + koff;
      size_t eb = (size_t)(n0 + row) * K + koff;
      int lbase = q * 2048 + wave * 512;
      gload_lds16(Ah_g + ea, Ahs + lbase);
      gload_lds16(Al_g + ea, Als + lbase);
      gload_lds16(Bh_g + eb, Bhs + lbase);
      gload_lds16(Bl_g + eb, Bls + lbase);
    }
    __syncthreads();
#pragma unroll
    for (int kf = 0; kf < 2; ++kf) {
      short8 ah[4], al[4];
#pragma unroll
      for (int mi = 0; mi < 4; ++mi) {
        int r_ = wm0 + mi * 16 + lr;
        int g = (kf * 4 + lg) ^ (r_ & 7);
        ah[mi] = *reinterpret_cast<const short8*>(&Ahs[r_ * 64 + g * 8]);
        al[mi] = *reinterpret_cast<const short8*>(&Als[r_ * 64 + g * 8]);
      }
#pragma unroll
      for (int ni = 0; ni < 4; ++ni) {
        int r_ = wn0 + ni * 16 + lr;
        int g = (kf * 4 + lg) ^ (r_ & 7);
        short8 bh8 = *reinterpret_cast<const short8*>(&Bhs[r_ * 64 + g * 8]);
        short8 bl8 = *reinterpret_cast<const short8*>(&Bls[r_ * 64 + g * 8]);
#pragma unroll
        for (int mi = 0; mi < 4; ++mi) {
          acc[mi][ni] = __builtin_amdgcn_mfma_f32_16x16x32_bf16(ah[mi], bh8, acc[mi][ni], 0, 0, 0);
          acc[mi][ni] = __builtin_amdgcn_mfma_f32_16x16x32_bf16(ah[mi], bl8, acc[mi][ni], 0, 0, 0);
          acc[mi][ni] = __builtin_amdgcn_mfma_f32_16x16x32_bf16(al[mi], bh8, acc[mi][ni], 0, 0, 0);
        }
      }
    }
    __syncthreads();
  }
#pragma unroll
  for (int mi = 0; mi < 4; ++mi)
#pragma unroll
    for (int ni = 0; ni < 4; ++ni) {
      int col = n0 + wn0 + ni * 16 + lr;
      float bvv = bias[col];
      f32x4 a = acc[mi][ni];
#pragma unroll
      for (int r = 0; r < 4; ++r) {
        int row = m0 + wm0 + mi * 16 + lg * 4 + r;
        Cf[(size_t)row * N + col] = a[r] + bvv;
      }
    }
}

// ---------------- fused rFFT*gate*irFFT + transpose + split output ----------------
// 16 waves / 16 columns per block; per-wave register FFT; final cross-wave LDS
// transpose writes y{h,l}[b][t][c0..c0+15] directly (no separate tysplit pass).
#define PADI(i) ((i) + ((i) >> 5))
#define ZSTRIDE 1057   // 1057 % 32 == 1 -> cross-buffer gather is bank-spread

template<int HJ, int TWS>
__device__ __forceinline__ void fwd_reg_stage(float* vr, float* vi,
    const float* TWr, const float* TWi, int lane) {
  float twr_[HJ], twi_[HJ];
#pragma unroll
  for (int t = 0; t < HJ; ++t) {
    int m = (t * 64 + lane) * TWS;
    twr_[t] = TWr[PADI(m)]; twi_[t] = TWi[PADI(m)];
  }
#pragma unroll
  for (int j = 0; j < 16; ++j) {
    if (j & HJ) continue;
    int t = j & (HJ - 1);
    float ur = vr[j], ui = vi[j];
    float wr = vr[j + HJ], wi = vi[j + HJ];
    float dr = ur - wr, di = ui - wi;
    vr[j] = ur + wr; vi[j] = ui + wi;
    vr[j + HJ] = dr * twr_[t] - di * twi_[t];
    vi[j + HJ] = dr * twi_[t] + di * twr_[t];
  }
}

template<int S, int TWS>
__device__ __forceinline__ void fwd_lane_stage(float* vr, float* vi,
    const float* TWr, const float* TWi, int lane) {
  float twr_ = 1.0f, twi_ = 0.0f;
  if (S > 1) {
    int m = (lane & (S - 1)) * TWS;
    twr_ = TWr[PADI(m)]; twi_ = TWi[PADI(m)];
  }
  bool hi = (lane & S) != 0;
#pragma unroll
  for (int j = 0; j < 16; ++j) {
    float or_ = __shfl_xor(vr[j], S, 64);
    float oi_ = __shfl_xor(vi[j], S, 64);
    float sr = vr[j] + or_, si_ = vi[j] + oi_;
    float dr = or_ - vr[j], di = oi_ - vi[j];
    float rr = dr * twr_ - di * twi_;
    float ri = dr * twi_ + di * twr_;
    vr[j] = hi ? rr : sr;
    vi[j] = hi ? ri : si_;
  }
}

template<int S, int TWS>
__device__ __forceinline__ void inv_lane_stage(float* vr, float* vi,
    const float* TWr, const float* TWi, int lane) {
  float twr_ = 1.0f, twi_ = 0.0f;
  if (S > 1) {
    int m = (lane & (S - 1)) * TWS;
    twr_ = TWr[PADI(m)]; twi_ = -TWi[PADI(m)];
  }
  bool hi = (lane & S) != 0;
#pragma unroll
  for (int j = 0; j < 16; ++j) {
    float xr = vr[j], xi = vi[j];
    if (S > 1) {
      float pr = xr * twr_ - xi * twi_;
      float pi = xr * twi_ + xi * twr_;
      xr = hi ? pr : xr;
      xi = hi ? pi : xi;
    }
    float or_ = __shfl_xor(xr, S, 64);
    float oi_ = __shfl_xor(xi, S, 64);
    vr[j] = hi ? (or_ - xr) : (xr + or_);
    vi[j] = hi ? (oi_ - xi) : (xi + oi_);
  }
}

template<int HJ, int TWS>
__device__ __forceinline__ void inv_reg_stage(float* vr, float* vi,
    const float* TWr, const float* TWi, int lane) {
  float twr_[HJ], twi_[HJ];
#pragma unroll
  for (int t = 0; t < HJ; ++t) {
    int m = (t * 64 + lane) * TWS;
    twr_[t] = TWr[PADI(m)]; twi_[t] = -TWi[PADI(m)];
  }
#pragma unroll
  for (int j = 0; j < 16; ++j) {
    if (j & HJ) continue;
    int t = j & (HJ - 1);
    float ur = vr[j], ui = vi[j];
    float br = vr[j + HJ], bi = vi[j + HJ];
    float wr = br * twr_[t] - bi * twi_[t];
    float wi = br * twi_[t] + bi * twr_[t];
    vr[j] = ur + wr; vi[j] = ui + wi;
    vr[j + HJ] = ur - wr; vi[j + HJ] = ui - wi;
  }
}

__global__ __launch_bounds__(1024) void conv_fft_kernel(
    const float* __restrict__ vT, const float* __restrict__ gateb,
    u16t* __restrict__ yh, u16t* __restrict__ yl) {
  __shared__ float Zr[16 * ZSTRIDE], Zi[16 * ZSTRIDE];   // 135.3 KB
  __shared__ float TWr[528], TWi[528];                    // 4.2 KB
  const int tid = threadIdx.x;
  const int lane = tid & 63, wave = tid >> 6;
  const int c0 = blockIdx.x * 16;
  const int b = blockIdx.y;
  const int bh = b * NHEAD + (c0 >> 6);
  const float* gate_bh = gateb + (size_t)bh * NFREQ * 2;

  if (tid < 512) {
    float si, co;
    sincosf(-3.14159265358979323846f * (float)tid * (1.0f / 512.0f), &si, &co);
    TWr[PADI(tid)] = co; TWi[PADI(tid)] = si;
  }
  __syncthreads();

  float* zr = Zr + wave * ZSTRIDE;
  float* zi = Zi + wave * ZSTRIDE;
  const float* col = vT + ((size_t)b * DMOD + (c0 + wave)) * NSEQ;

  float vr[16], vi[16];
#pragma unroll
  for (int j = 0; j < 16; ++j) {
    float2 w2 = *reinterpret_cast<const float2*>(col + 2 * (j * 64 + lane));
    vr[j] = w2.x; vi[j] = w2.y;
  }

  fwd_reg_stage<8, 1>(vr, vi, TWr, TWi, lane);
  fwd_reg_stage<4, 2>(vr, vi, TWr, TWi, lane);
  fwd_reg_stage<2, 4>(vr, vi, TWr, TWi, lane);
  fwd_reg_stage<1, 8>(vr, vi, TWr, TWi, lane);
  fwd_lane_stage<32, 16>(vr, vi, TWr, TWi, lane);
  fwd_lane_stage<16, 32>(vr, vi, TWr, TWi, lane);
  fwd_lane_stage<8, 64>(vr, vi, TWr, TWi, lane);
  fwd_lane_stage<4, 128>(vr, vi, TWr, TWi, lane);
  fwd_lane_stage<2, 256>(vr, vi, TWr, TWi, lane);
  fwd_lane_stage<1, 0>(vr, vi, TWr, TWi, lane);

#pragma unroll
  for (int j = 0; j < 16; ++j) {
    int p = PADI(j * 64 + lane);
    zr[p] = vr[j]; zi[p] = vi[j];
  }
  asm volatile("s_waitcnt lgkmcnt(0)" ::: "memory");

  const float s1 = 1.0f / 1024.0f;
#pragma unroll
  for (int q = 0; q < 8; ++q) {
    int k = q * 64 + lane;
    if (k == 0) {
      float z0r = zr[0], z0i = zi[0];
      float X0 = z0r + z0i;
      float XN = z0r - z0i;
      float2 G0 = *reinterpret_cast<const float2*>(gate_bh + 0);
      float2 GN = *reinterpret_cast<const float2*>(gate_bh + 1024 * 2);
      float y0 = X0 * G0.x * s1;
      float yN = XN * GN.x * s1;
      zr[0] = 0.5f * (y0 + yN); zi[0] = 0.5f * (y0 - yN);
      float zmr = zr[1], zmi = zi[1];
      float X5r = zmr, X5i = -zmi;
      float2 G5 = *reinterpret_cast<const float2*>(gate_bh + 512 * 2);
      float Y5r = (X5r * G5.x - X5i * G5.y) * s1;
      float Y5i = (X5r * G5.y + X5i * G5.x) * s1;
      zr[1] = Y5r; zi[1] = -Y5i;
    } else {
      int kq = 1024 - k;
      int rp = PADI((int)(__brev((unsigned)k) >> 22));
      int rq = PADI((int)(__brev((unsigned)kq) >> 22));
      float Zkr = zr[rp], Zki = zi[rp];
      float Zqr = zr[rq], Zqi = zi[rq];
      float Er = 0.5f * (Zkr + Zqr), Ei = 0.5f * (Zki - Zqi);
      float Odr = 0.5f * (Zki + Zqi), Odi = -0.5f * (Zkr - Zqr);
      float ti, tr;
      sincosf(-3.14159265358979323846f * (float)k * (1.0f / 1024.0f), &ti, &tr);
      float Pr = Odr * tr - Odi * ti, Pi = Odr * ti + Odi * tr;
      float Xkr = Er + Pr, Xki = Ei + Pi;
      float Xqr = Er - Pr, Xqi = -(Ei - Pi);
      float2 Gk = *reinterpret_cast<const float2*>(gate_bh + k * 2);
      float2 Gq = *reinterpret_cast<const float2*>(gate_bh + kq * 2);
      float Ykr = (Xkr * Gk.x - Xki * Gk.y) * s1;
      float Yki = (Xkr * Gk.y + Xki * Gk.x) * s1;
      float Yqr = (Xqr * Gq.x - Xqi * Gq.y) * s1;
      float Yqi = (Xqr * Gq.y + Xqi * Gq.x) * s1;
      float E2r = 0.5f * (Ykr + Yqr), E2i = 0.5f * (Yki - Yqi);
      float D2r = 0.5f * (Ykr - Yqr), D2i = 0.5f * (Yki + Yqi);
      float O2r = D2r * tr + D2i * ti, O2i = D2i * tr - D2r * ti;
      zr[rp] = E2r - O2i; zi[rp] = E2i + O2r;
      zr[rq] = E2r + O2i; zi[rq] = O2r - E2i;
    }
  }
  asm volatile("s_waitcnt lgkmcnt(0)" ::: "memory");

#pragma unroll
  for (int j = 0; j < 16; ++j) {
    int p = PADI(j * 64 + lane);
    vr[j] = zr[p]; vi[j] = zi[p];
  }
  asm volatile("s_waitcnt lgkmcnt(0)" ::: "memory");

  inv_lane_stage<1, 0>(vr, vi, TWr, TWi, lane);
  inv_lane_stage<2, 256>(vr, vi, TWr, TWi, lane);
  inv_lane_stage<4, 128>(vr, vi, TWr, TWi, lane);
  inv_lane_stage<8, 64>(vr, vi, TWr, TWi, lane);
  inv_lane_stage<16, 32>(vr, vi, TWr, TWi, lane);
  inv_lane_stage<32, 16>(vr, vi, TWr, TWi, lane);
  inv_reg_stage<1, 8>(vr, vi, TWr, TWi, lane);
  inv_reg_stage<2, 4>(vr, vi, TWr, TWi, lane);
  inv_reg_stage<4, 2>(vr, vi, TWr, TWi, lane);
  inv_reg_stage<8, 1>(vr, vi, TWr, TWi, lane);

  // dump natural-order y (z'[n] = y[2n] + i y[2n+1]) into per-wave Z buffer
#pragma unroll
  for (int j = 0; j < 16; ++j) {
    int p = PADI(j * 64 + lane);
    zr[p] = vr[j]; zi[p] = vi[j];
  }
  __syncthreads();

  // transpose+split: thread n gathers rows t=2n, 2n+1 across 16 columns
  {
    alignas(16) u16t he[16], le[16], ho[16], lo_[16];
    int p = PADI(tid);
#pragma unroll
    for (int w = 0; w < 16; ++w) {
      float re = Zr[w * ZSTRIDE + p];
      float im = Zi[w * ZSTRIDE + p];
      u16t hr = bf16_rtn(re);
      he[w] = hr; le[w] = bf16_rtn(re - bf16f(hr));
      u16t hm = bf16_rtn(im);
      ho[w] = hm; lo_[w] = bf16_rtn(im - bf16f(hm));
    }
    size_t o0 = ((size_t)b * NSEQ + 2 * tid) * DMOD + c0;
    size_t o1 = o0 + DMOD;
    *reinterpret_cast<uint4*>(yh + o0) = reinterpret_cast<const uint4*>(he)[0];
    *reinterpret_cast<uint4*>(yh + o0 + 8) = reinterpret_cast<const uint4*>(he)[1];
    *reinterpret_cast<uint4*>(yl + o0) = reinterpret_cast<const uint4*>(le)[0];
    *reinterpret_cast<uint4*>(yl + o0 + 8) = reinterpret_cast<const uint4*>(le)[1];
    *reinterpret_cast<uint4*>(yh + o1) = reinterpret_cast<const uint4*>(ho)[0];
    *reinterpret_cast<uint4*>(yh + o1 + 8) = reinterpret_cast<const uint4*>(ho)[1];
    *reinterpret_cast<uint4*>(yl + o1) = reinterpret_cast<const uint4*>(lo_)[0];
    *reinterpret_cast<uint4*>(yl + o1 + 8) = reinterpret_cast<const uint4*>(lo_)[1];
  }
}

// ---------------- pooled g partials + inline softmax stats (from s_part) ----------------
__global__ __launch_bounds__(256) void pool_partial_kernel(
    const float* __restrict__ x, const float* __restrict__ s_part,
    const float* __restrict__ bp2, float* __restrict__ gpart) {
  int chunk = blockIdx.x, b = blockIdx.y;   // (16, 4)
  int tid = threadIdx.x;
  __shared__ float red[256];
  __shared__ float wsh[128];
  float bp = bp2[0];
  float sv[8];
  float m = -1e30f;
#pragma unroll
  for (int q = 0; q < 8; ++q) {
    int row = b * NSEQ + q * 256 + tid;
    float v = bp;
#pragma unroll
    for (int c = 0; c < 8; ++c) v += s_part[c * 8192 + row];
    sv[q] = v;
    m = fmaxf(m, v);
  }
  red[tid] = m; __syncthreads();
  for (int o = 128; o; o >>= 1) { if (tid < o) red[tid] = fmaxf(red[tid], red[tid + o]); __syncthreads(); }
  float bm = red[0]; __syncthreads();
  float sum = 0.f;
#pragma unroll
  for (int q = 0; q < 8; ++q) sum += expf(sv[q] - bm);
  red[tid] = sum; __syncthreads();
  for (int o = 128; o; o >>= 1) { if (tid < o) red[tid] += red[tid + o]; __syncthreads(); }
  float inv = 1.0f / red[0];
  __syncthreads();
  int n0 = chunk * 128;
  if (tid < 128) {
    int row = b * NSEQ + n0 + tid;
    float v = bp;
#pragma unroll
    for (int c = 0; c < 8; ++c) v += s_part[c * 8192 + row];
    wsh[tid] = expf(v - bm) * inv;
  }
  __syncthreads();
  float acc[4] = {};
  for (int n = 0; n < 128; ++n) {
    float wn = wsh[n];
    const float* xr = &x[((size_t)b * NSEQ + n0 + n) * DMOD];
#pragma unroll
    for (int q = 0; q < 4; ++q) acc[q] = fmaf(wn, xr[tid + 256 * q], acc[q]);
  }
  float* gp = &gpart[((size_t)b * 16 + chunk) * DMOD];
#pragma unroll
  for (int q = 0; q < 4; ++q) gp[tid + 256 * q] = acc[q];
}

// ---------------- fused pool-reduce + MLP1 partial ----------------
__global__ __launch_bounds__(256) void pool_reduce_mlp1_kernel(
    const float* __restrict__ gpart, const float* __restrict__ Wg1,
    float* __restrict__ part1) {
  int kb = blockIdx.x, b = blockIdx.y;
  int tid = threadIdx.x;
  int k0 = kb * 64;
  __shared__ float g_s[64];
  if (tid < 64) {
    float acc = 0.f;
#pragma unroll
    for (int j = 0; j < 16; ++j)
      acc += gpart[((size_t)b * 16 + j) * DMOD + k0 + tid];
    g_s[tid] = acc;
  }
  __syncthreads();
  float acc = 0.f;
#pragma unroll 8
  for (int i = 0; i < 64; ++i)
    acc = fmaf(g_s[i], Wg1[(size_t)(k0 + i) * 256 + tid], acc);
  part1[((size_t)b * 16 + kb) * 256 + tid] = acc;
}

// ---------------- gate: part1-reduce + gelu + MLP2 (inline) + resize + modReLU + conv ----------------
__device__ __forceinline__ float keys_cubic(float x) {
  if (x >= 2.0f) return 0.0f;
  if (x >= 1.0f) return ((-0.5f * x + 2.5f) * x - 4.0f) * x + 2.0f;
  return ((1.5f * x - 2.5f) * x) * x + 1.0f;
}

__global__ __launch_bounds__(256) void gate_kernel(
    const float* __restrict__ part1, const float* __restrict__ bg1,
    const float* __restrict__ Wg2, const float* __restrict__ bg2,
    const float* __restrict__ mod_bias,
    const float* __restrict__ kr5, const float* __restrict__ ki5,
    float* __restrict__ gate_out) {
  int bh = blockIdx.x;
  int tid = threadIdx.x;
  __shared__ float hs_s[256];
  __shared__ float anch_s[64];
  __shared__ float ar_[32], ai_[32];
  __shared__ float gr[NFREQ], gi[NFREQ];
  int b = bh >> 4, h = bh & 15;
  {
    float a1 = bg1[tid];
#pragma unroll
    for (int j = 0; j < 16; ++j)
      a1 += part1[((size_t)b * 16 + j) * 256 + tid];
    hs_s[tid] = gelu_exact(a1);
  }
  __syncthreads();
  if (tid < 64) {
    int cc = h * 64 + tid;
    float a2 = bg2[cc];
    for (int i = 0; i < 256; ++i) a2 = fmaf(hs_s[i], Wg2[(size_t)i * 1024 + cc], a2);
    anch_s[tid] = a2;
  }
  __syncthreads();
  if (tid < 32) {
    ar_[tid] = anch_s[tid * 2 + 0];
    ai_[tid] = anch_s[tid * 2 + 1];
  }
  __syncthreads();
  const float inv_scale = 32.0f / 1025.0f;
  for (int f = tid; f < NFREQ; f += 256) {
    float c = (f + 0.5f) * inv_scale - 0.5f;
    int j0 = (int)floorf(c) - 1;
    float wr = 0.f, wi = 0.f, wsum = 0.f;
#pragma unroll
    for (int u = 0; u < 4; ++u) {
      int j = j0 + u;
      if (j < 0 || j > 31) continue;
      float w = keys_cubic(fabsf(c - (float)j));
      wsum += w;
      wr = fmaf(w, ar_[j], wr);
      wi = fmaf(w, ai_[j], wi);
    }
    float invw = 1.0f / wsum;
    wr *= invw; wi *= invw;
    float mag = sqrtf(wr * wr + wi * wi);
    float scale = fmaxf(mag + mod_bias[f], 0.0f) / (mag + 1e-8f);
    gr[f] = wr * scale;
    gi[f] = wi * scale;
  }
  __syncthreads();
  float k_r[5], k_i[5];
#pragma unroll
  for (int j = 0; j < 5; ++j) { k_r[j] = kr5[j]; k_i[j] = ki5[j]; }
  for (int f = tid; f < NFREQ; f += 256) {
    float cr = 0.f, ci = 0.f;
#pragma unroll
    for (int j = 0; j < 5; ++j) {
      int idx = f + j - 2;
      if (idx < 0) idx += NFREQ;
      else if (idx >= NFREQ) idx -= NFREQ;
      float a = gr[idx], bb = gi[idx];
      cr = fmaf(k_r[j], a, cr); cr = fmaf(-k_i[j], bb, cr);
      ci = fmaf(k_r[j], bb, ci); ci = fmaf(k_i[j], a, ci);
    }
    gate_out[((size_t)bh * NFREQ + f) * 2 + 0] = cr;
    gate_out[((size_t)bh * NFREQ + f) * 2 + 1] = ci;
  }
}

extern "C" void kernel_launch(void* const* d_in, const int* in_sizes, int n_in,
                              void* d_out, int out_size, void* d_ws, size_t ws_size,
                              hipStream_t stream) {
  const float* x        = (const float*)d_in[0];
  const float* Wv       = (const float*)d_in[1];
  const float* bv       = (const float*)d_in[2];
  const float* Wp1      = (const float*)d_in[3];
  const float* bp1      = (const float*)d_in[4];
  const float* Wp2      = (const float*)d_in[5];
  const float* bp2      = (const float*)d_in[6];
  const float* Wg1      = (const float*)d_in[7];
  const float* bg1      = (const float*)d_in[8];
  const float* Wg2      = (const float*)d_in[9];
  const float* bg2      = (const float*)d_in[10];
  const float* mod_bias = (const float*)d_in[11];
  const float* ckr      = (const float*)d_in[12];
  const float* cki      = (const float*)d_in[13];
  const float* Wo       = (const float*)d_in[14];
  const float* bo       = (const float*)d_in[15];

  const int M = NBATCH * NSEQ;          // 8192
  const size_t MD = (size_t)M * DMOD;   // 8M elems
  char* wsb = (char*)d_ws;

  // ---- ws layout (peak ~37.25 MB, lifetime-aliased; same as R11) ----
  u16t* x_hi = (u16t*)wsb;                               // [0,16M)   ; later y_hi
  u16t* x_lo = x_hi + MD;                                // [16M,32M) ; later y_lo
  u16t* y_hi = x_hi;
  u16t* y_lo = x_lo;
  u16t* WT_h = (u16t*)(wsb + (size_t)32 * 1024 * 1024);  // [32M,34M) Wv^T, then Wo^T
  u16t* WT_l = (u16t*)(wsb + (size_t)34 * 1024 * 1024);  // [34M,36M)
  u16t* WTp1_h = (u16t*)(wsb + (size_t)36 * 1024 * 1024);          // [36M,36.5M)
  u16t* WTp1_l = (u16t*)(wsb + (size_t)36 * 1024 * 1024 + 524288); // [36.5M,37M)
  float* s_part = (float*)(wsb + (size_t)37 * 1024 * 1024);        // 256 KB [37M,37.25M)
  // after fused GEMM, WTp1 window [36M,37M) dead -> gpart/part1/gateb (785 KB):
  float* gpart = (float*)(wsb + (size_t)36 * 1024 * 1024);         // 256 KB
  float* part1 = gpart + 65536;                                    // 16 KB
  float* gateb = part1 + 4096;                                     // 513 KB

  // d_out staging: vT fp32 (32 MB) -> final out fp32
  float* vT  = (float*)d_out;
  float* out = (float*)d_out;

  dim3 blk(256);

  // 1. split x -> bf16 hi/lo
  split_kernel<<<dim3(2048), blk, 0, stream>>>(x, x_hi, x_lo, (int)(MD / 8));
  // 2. merged weight transposes: Wv^T + Wp1^T
  tsplit2_kernel<<<dim3(40, 32), blk, 0, stream>>>(Wv, WT_h, WT_l, Wp1, WTp1_h, WTp1_l);
  // 3. fused GEMM (512 blocks): vT + s_part
  gemm_fused_kernel<<<dim3(512), blk, 0, stream>>>(
      x_hi, x_lo, WT_h, WT_l, WTp1_h, WTp1_l, bv, bp1, Wp2, vT, s_part);
  // 4. Wo^T transpose (Wv^T dead)
  tsplit_kernel<<<dim3(1024 / 32, 1024 / 32), blk, 0, stream>>>(Wo, WT_h, WT_l, 1024, 1024);
  // 5. pooled g partials with inline softmax stats (WTp1 window now gpart/...)
  pool_partial_kernel<<<dim3(16, NBATCH), blk, 0, stream>>>(x, s_part, bp2, gpart);
  // 6. gate MLP1 partial, then gate kernel (inline MLP2)
  pool_reduce_mlp1_kernel<<<dim3(16, NBATCH), blk, 0, stream>>>(gpart, Wg1, part1);
  gate_kernel<<<dim3(NBATCH * NHEAD), blk, 0, stream>>>(
      part1, bg1, Wg2, bg2, mod_bias, ckr, cki, gateb);
  // 7. fused rFFT*gate*irFFT + transpose + split -> y (overwrites x split; x dead)
  conv_fft_kernel<<<dim3(DMOD / 16, NBATCH), dim3(1024), 0, stream>>>(
      vT, gateb, y_hi, y_lo);
  // 8. GEMM3: out = y @ Wo + bo (overwrites vT; dead)
  mfma_gemm<8><<<dim3((DMOD / 128) * (M / 128)), blk, 0, stream>>>(
      y_hi, y_lo, WT_h, WT_l, bo, out, DMOD, 1024);
}